// Round 10
// baseline (732.346 us; speedup 1.0000x reference)
//
#include <hip/hip_runtime.h>

// ---------------- types ----------------
typedef __bf16 bf16x8 __attribute__((ext_vector_type(8)));
typedef float f32x4 __attribute__((ext_vector_type(4)));

__device__ __forceinline__ unsigned short f2bf(float f) {
    unsigned int u = __builtin_bit_cast(unsigned int, f);
    u += 0x7FFFu + ((u >> 16) & 1u);
    return (unsigned short)(u >> 16);
}

// ---------------- weight f32 -> bf16 conversion ----------------
__global__ void cvt_kernel(const float* __restrict__ in,
                           unsigned short* __restrict__ out, long n4) {
    long i = (long)blockIdx.x * blockDim.x + threadIdx.x;
    long stride = (long)gridDim.x * blockDim.x;
    for (; i < n4; i += stride) {
        float4 v = ((const float4*)in)[i];
        ushort4 o;
        o.x = f2bf(v.x); o.y = f2bf(v.y); o.z = f2bf(v.z); o.w = f2bf(v.w);
        ((ushort4*)out)[i] = o;
    }
}

// ---------------- fused 2-token attention -> h0 (bf16) ----------------
__global__ __launch_bounds__(256) void attn_kernel(
    const float* __restrict__ x1, const float* __restrict__ x2,
    unsigned short* __restrict__ h) {
    const int D = 1024;
    const int lane = threadIdx.x & 63;
    const int wave = threadIdx.x >> 6;
    const long row = (long)blockIdx.x * 4 + wave;
    const float4* p1 = (const float4*)(x1 + row * D);
    const float4* p2 = (const float4*)(x2 + row * D);
    float4 v1[4], v2[4];
    float s11 = 0.f, s12 = 0.f, s22 = 0.f;
#pragma unroll
    for (int j = 0; j < 4; ++j) {
        v1[j] = p1[lane + 64 * j];
        v2[j] = p2[lane + 64 * j];
        s11 += v1[j].x * v1[j].x + v1[j].y * v1[j].y + v1[j].z * v1[j].z + v1[j].w * v1[j].w;
        s12 += v1[j].x * v2[j].x + v1[j].y * v2[j].y + v1[j].z * v2[j].z + v1[j].w * v2[j].w;
        s22 += v2[j].x * v2[j].x + v2[j].y * v2[j].y + v2[j].z * v2[j].z + v2[j].w * v2[j].w;
    }
#pragma unroll
    for (int off = 1; off < 64; off <<= 1) {
        s11 += __shfl_xor(s11, off);
        s12 += __shfl_xor(s12, off);
        s22 += __shfl_xor(s22, off);
    }
    const float a00 = 1.f / (1.f + expf((s12 - s11) * (1.f / 32.f)));
    const float a10 = 1.f / (1.f + expf((s22 - s12) * (1.f / 32.f)));
    const float a01 = 1.f - a00, a11 = 1.f - a10;
    unsigned short* h0 = h + row * 2048;
#pragma unroll
    for (int j = 0; j < 4; ++j) {
        const int f = lane + 64 * j;
        ushort4 o0, o1;
        o0.x = f2bf(a00 * v1[j].x + a01 * v2[j].x);
        o0.y = f2bf(a00 * v1[j].y + a01 * v2[j].y);
        o0.z = f2bf(a00 * v1[j].z + a01 * v2[j].z);
        o0.w = f2bf(a00 * v1[j].w + a01 * v2[j].w);
        o1.x = f2bf(a10 * v1[j].x + a11 * v2[j].x);
        o1.y = f2bf(a10 * v1[j].y + a11 * v2[j].y);
        o1.z = f2bf(a10 * v1[j].z + a11 * v2[j].z);
        o1.w = f2bf(a10 * v1[j].w + a11 * v2[j].w);
        ((ushort4*)(h0))[f] = o0;
        ((ushort4*)(h0 + 1024))[f] = o1;
    }
}

// ---- 128x256 GEMM, 2 blocks/CU: C = act(A[M,K] * Bw[N,K]^T + bias) --------
// 8 waves (2Mx4N), per-wave 64x64 (acc 4x4 f32x4 = 64 regs). BK=32.
// LDS: 3 slots x 24 KiB (A 8K [128x32] | B 16K [256x32], 64B pitch) = 72 KiB
// -> 2 blocks/CU (TLP hides barrier/lgkm/vm waits). One phase per K-tile:
// {stage t+2 (3 gload_lds); 8 ds_read; MFMA x16; VMW(3); BAR}. st_16x32
// swizzle on stage-source AND read addr (same involution as prior rounds).
#define BAR   __builtin_amdgcn_s_barrier()
#define VMW3  asm volatile("s_waitcnt vmcnt(3)" ::: "memory")
#define VMW0  asm volatile("s_waitcnt vmcnt(0)" ::: "memory")
#define PRIO1 __builtin_amdgcn_s_setprio(1)
#define PRIO0 __builtin_amdgcn_s_setprio(0)

template <bool RELU, typename OT>
__global__ __launch_bounds__(512, 4) void gemm128(
    const unsigned short* __restrict__ A,   // [M,K] bf16 (activations)
    const unsigned short* __restrict__ Bw,  // [N,K] bf16 (weights)
    const float* __restrict__ bias,         // [N]
    OT* __restrict__ C,                     // [M,N]
    int N, int K) {
    __shared__ __align__(16) unsigned short lds[36864];  // 72 KiB
    const int tid = threadIdx.x;
    const int lane = tid & 63, wave = tid >> 6;
    const int wm = wave >> 2, wn = wave & 3;
    const int fr = lane & 15, fq = lane >> 4;

    // XCD swizzle; bm fastest so consecutive swz share the B-panel (bn).
    const int cpx = (int)gridDim.x >> 3;
    const int swz = ((int)blockIdx.x & 7) * cpx + ((int)blockIdx.x >> 3);
    const int bm = swz & 127;
    const int bn = swz >> 7;
    const long m0 = (long)bm * 128, n0 = (long)bn * 256;
    const long rowb = (long)K * 2;

    // read addressing: slot*24576 + region + row*64 + (fq*16 ^ flip)
    const int flip = ((fr >> 3) & 1) << 5;
    const int lbase = fr * 64 + ((fq * 16) ^ flip);
    const int aRd = wm * 4096 + lbase;            // + mq*1024
    const int bRd = 8192 + wn * 4096 + lbase;     // + nf*1024
    const char* ldsc = (const char*)lds;

    // staging: wave stages 3 chunks per K-tile: A rows [w*16,+16),
    // B rows [w*16,+16), B rows [128+w*16,+16). Linear LDS dest
    // (chunk*1024 + lane*16), pre-swizzled global source column.
    const int srow = lane >> 2;
    const int scol = ((lane & 3) << 4) ^ ((lane >> 5) << 5);
    const char* Abl = (const char*)A + m0 * rowb;
    const char* Bbl = (const char*)Bw + n0 * rowb;
    const char* s0 = Abl + (long)(wave * 16 + srow) * rowb + scol;
    const char* s1 = Bbl + (long)(wave * 16 + srow) * rowb + scol;
    const char* s2 = Bbl + (long)(128 + wave * 16 + srow) * rowb + scol;
    const int d0 = wave * 1024 + lane * 16;            // A region
    const int d1 = 8192 + wave * 1024 + lane * 16;     // B rows 0-127
    const int d2 = 16384 + wave * 1024 + lane * 16;    // B rows 128-255

    auto gl = [&](const char* src, int dst) {
        __builtin_amdgcn_global_load_lds(
            (const __attribute__((address_space(1))) void*)src,
            (__attribute__((address_space(3))) void*)((char*)lds + dst),
            16, 0, 0);
    };
    auto stage = [&](int kt, int slot) {
        const long ko = (long)kt * 64;
        const int sb = slot * 24576;
        gl(s0 + ko, sb + d0);
        gl(s1 + ko, sb + d1);
        gl(s2 + ko, sb + d2);
    };

    f32x4 acc[4][4] = {};
    bf16x8 Af[4], Bf[4];

    // ---- prologue: t0 -> slot0, t1 -> slot1; wait t0; barrier ----
    stage(0, 0);
    stage(1, 1);
    VMW3;
    BAR;

    const int NT = K >> 5;   // K-tiles of 32
    int sl = 0;
    for (int t = 0; t < NT; ++t) {
        const bool g = (t + 2 < NT);
        if (g) { const int ss = (sl == 0) ? 2 : sl - 1; stage(t + 2, ss); }
        const int sb = sl * 24576;
#pragma unroll
        for (int mq = 0; mq < 4; ++mq)
            Af[mq] = *(const bf16x8*)(ldsc + sb + aRd + mq * 1024);
#pragma unroll
        for (int nf = 0; nf < 4; ++nf)
            Bf[nf] = *(const bf16x8*)(ldsc + sb + bRd + nf * 1024);
        PRIO1;
#pragma unroll
        for (int nf = 0; nf < 4; ++nf)
#pragma unroll
            for (int mq = 0; mq < 4; ++mq)
                acc[mq][nf] = __builtin_amdgcn_mfma_f32_16x16x32_bf16(
                    Bf[nf], Af[mq], acc[mq][nf], 0, 0, 0);
        PRIO0;
        if (g) { VMW3; } else { VMW0; }
        BAR;
        sl = (sl == 2) ? 0 : sl + 1;
    }

    // ---- epilogue: swapped layout => lane owns row (fr) x 4 consecutive cols
    const long crow0 = m0 + wm * 64 + fr;
    const long ccol0 = n0 + wn * 64 + fq * 4;
#pragma unroll
    for (int m = 0; m < 4; ++m) {
        const long rb = (crow0 + m * 16) * N;
#pragma unroll
        for (int n = 0; n < 4; ++n) {
            const float4 bv = *(const float4*)(bias + ccol0 + n * 16);
            float v0 = acc[m][n][0] + bv.x;
            float v1 = acc[m][n][1] + bv.y;
            float v2 = acc[m][n][2] + bv.z;
            float v3 = acc[m][n][3] + bv.w;
            if (RELU) {
                v0 = v0 > 0.f ? v0 : 0.f; v1 = v1 > 0.f ? v1 : 0.f;
                v2 = v2 > 0.f ? v2 : 0.f; v3 = v3 > 0.f ? v3 : 0.f;
            }
            if constexpr (sizeof(OT) == 2) {
                uint2 oo;
                oo.x = (unsigned)f2bf(v0) | ((unsigned)f2bf(v1) << 16);
                oo.y = (unsigned)f2bf(v2) | ((unsigned)f2bf(v3) << 16);
                *(uint2*)((unsigned short*)C + rb + ccol0 + n * 16) = oo;
            } else {
                *(float4*)((float*)C + rb + ccol0 + n * 16) =
                    make_float4(v0, v1, v2, v3);
            }
        }
    }
}

// ---------------- launch ----------------
extern "C" void kernel_launch(void* const* d_in, const int* in_sizes, int n_in,
                              void* d_out, int out_size, void* d_ws, size_t ws_size,
                              hipStream_t stream) {
    const float* x1 = (const float*)d_in[0];
    const float* x2 = (const float*)d_in[1];
    const float* Ws = (const float*)d_in[2];   // [4,2048,2048]
    const float* bs = (const float*)d_in[3];   // [4,2048]
    const float* Wl = (const float*)d_in[4];   // [1024,2048]
    const float* bl = (const float*)d_in[5];   // [1024]
    float* out = (float*)d_out;                // [16384,1024]

    char* ws = (char*)d_ws;
    unsigned short* hA  = (unsigned short*)(ws);                  // 64 MiB
    unsigned short* hB  = (unsigned short*)(ws + (67108864L));    // 64 MiB
    unsigned short* Wbf = (unsigned short*)(ws + (134217728L));   // 32 MiB
    unsigned short* Wlb = (unsigned short*)(ws + (167772160L));   // 4 MiB

    cvt_kernel<<<2048, 256, 0, stream>>>(Ws, Wbf, 4L * 2048 * 2048 / 4);
    cvt_kernel<<<512, 256, 0, stream>>>(Wl, Wlb, 1024L * 2048 / 4);

    attn_kernel<<<16384 / 4, 256, 0, stream>>>(x1, x2, hA);

    // MLP: 4x relu GEMM (bf16 ping-pong) + final GEMM (f32 out)
    // grid = (M/128) x (N/256): 128*8 = 1024 (layers), 128*4 = 512 (final)
    gemm128<true, unsigned short><<<1024, 512, 0, stream>>>(hA, Wbf + 0L * 2048 * 2048, bs + 0 * 2048, hB, 2048, 2048);
    gemm128<true, unsigned short><<<1024, 512, 0, stream>>>(hB, Wbf + 1L * 2048 * 2048, bs + 1 * 2048, hA, 2048, 2048);
    gemm128<true, unsigned short><<<1024, 512, 0, stream>>>(hA, Wbf + 2L * 2048 * 2048, bs + 2 * 2048, hB, 2048, 2048);
    gemm128<true, unsigned short><<<1024, 512, 0, stream>>>(hB, Wbf + 3L * 2048 * 2048, bs + 3 * 2048, hA, 2048, 2048);
    gemm128<false, float><<<512, 512, 0, stream>>>(hA, Wlb, bl, out, 1024, 2048);
}